// Round 2
// baseline (1772.142 us; speedup 1.0000x reference)
//
#include <hip/hip_runtime.h>

// ---------------------------------------------------------------------------
// FutureCameraHead on MI355X (gfx950)
// This rev: FUSED ResConvBlock trunk. Each 64-row strip lives in LDS (64 KB);
// one 512-thread block runs all 3 Linear+ReLU layers in place (weights stream
// from L2), then adds the residual (X re-read, mostly L2-hit) and writes back.
// Trunk: 6 GEMM dispatches (~1.9 GB HBM traffic) -> 2 fused dispatches
// (~0.8 GB). bf16 rounding between layers identical to the old 6-dispatch
// chain; final layer staged fp32 in LDS so residual-add rounding is unchanged.
// Tail (rows<=192) in fp32. 3x3 SVD orthogonalize via fp64 Jacobi + Kabsch.
// ---------------------------------------------------------------------------

typedef unsigned short u16;
typedef __attribute__((ext_vector_type(8))) short short8;   // 8 x bf16 (4 VGPRs)
typedef __attribute__((ext_vector_type(4))) float f32x4;    // MFMA acc

constexpr int  DDIM    = 512;
constexpr long R_ROWS  = 96L * 1369L;   // 131424 (BN * hw)
constexpr long R_PAD   = 2054L * 64L;   // 131456 buffer rows (multiple of 64)

__device__ __forceinline__ u16 f2b(float f) {  // fp32 -> bf16 RNE
  union { float f; unsigned u; } x; x.f = f;
  unsigned r = (x.u + 0x7FFFu + ((x.u >> 16) & 1u)) >> 16;
  return (u16)r;
}
__device__ __forceinline__ float b2f(u16 b) {
  union { unsigned u; float f; } x; x.u = ((unsigned)b) << 16;
  return x.f;
}

// --- feat fp32 -> bf16 padded buffer (pad rows zeroed) ----------------------
__global__ void convert_feat_k(const float* __restrict__ in, u16* __restrict__ out) {
  long i4 = ((long)blockIdx.x * 256 + threadIdx.x) * 4;
  if (i4 >= R_PAD * DDIM) return;
  ushort4 o;
  if (i4 < R_ROWS * DDIM) {
    float4 v = *(const float4*)(in + i4);
    o.x = f2b(v.x); o.y = f2b(v.y); o.z = f2b(v.z); o.w = f2b(v.w);
  } else {
    o.x = 0; o.y = 0; o.z = 0; o.w = 0;
  }
  *(ushort4*)(out + i4) = o;
}

// --- W_res [6][K=512][N=512] fp32 -> Wt [6][N][K] bf16 ----------------------
__global__ void transpose_w_k(const float* __restrict__ W, u16* __restrict__ Wt) {
  int idx = blockIdx.x * 256 + threadIdx.x;
  if (idx >= 6 * 512 * 512) return;
  int g = idx >> 18, rem = idx & 262143;
  int n = rem >> 9, k = rem & 511;
  Wt[idx] = f2b(W[(long)g * 262144 + (long)k * 512 + n]);
}

// --- fused ResConvBlock: A[strip] = A[strip] + relu(L2(relu(L1(relu(L0(A)))))
// Strip = 64 rows x 512 cols, held in LDS as bf16 (64 KB), XOR-swizzled
// 16B chunks: LDS slot (r, cS) holds global chunk cS ^ (r&7)  -> conflict-free
// ds_read_b128 A-fragments (2 lanes/bank = free).
// 8 waves: wave wn owns output cols [wn*64, wn*64+64) for ALL 64 rows.
// Weights (Wt layout [n][k], bf16) streamed from L2 as 16B register frags,
// double-buffered one kk-step ahead. acc: 4x4 f32x4 = 64 VGPR/lane.
// Final layer: staged fp32 in LDS (two 32-row halves re-using the same 64 KB)
// -> residual add in fp32 -> single bf16 round -> coalesced short8 store.
__global__ __launch_bounds__(512, 2)
void fused_res_k(u16* __restrict__ A, const u16* __restrict__ Wt3,
                 const float* __restrict__ bias3) {
  __shared__ __align__(16) u16 S[64 * 512];   // 64 KB
  float* S32 = (float*)S;                      // aliased for the final layer
  const int tid  = threadIdx.x;
  const int lane = tid & 63;
  const int wn   = tid >> 6;      // wave id 0..7 -> col group
  const int l15  = lane & 15;
  const int quad = lane >> 4;
  const long rowBase = (long)blockIdx.x * 64;

  // ---- stage X strip: LDS linear dest (global_load_lds), pre-swizzled source
#pragma unroll
  for (int j = 0; j < 8; ++j) {
    int L = tid + 512 * j;          // chunk slot 0..4095
    int r = L >> 6, cS = L & 63;
    int c = cS ^ (r & 7);           // global chunk this slot holds
    const u16* ga = A + (rowBase + r) * DDIM + c * 8;
    __builtin_amdgcn_global_load_lds(
        (const __attribute__((address_space(1))) void*)ga,
        (__attribute__((address_space(3))) void*)&S[L * 8], 16, 0, 0);
  }
  __syncthreads();

  for (int layer = 0; layer < 3; ++layer) {
    const u16*  W    = Wt3 + (long)layer * 262144;
    const float* bias = bias3 + layer * 512;

    f32x4 acc[4][4];
#pragma unroll
    for (int i = 0; i < 4; ++i)
#pragma unroll
      for (int j = 0; j < 4; ++j) acc[i][j] = (f32x4){0.f, 0.f, 0.f, 0.f};

    // B-frag base: col n = wn*64 + j*16 + l15 ; k-offset = kk*32 + quad*8
    const u16* wb = W + (long)(wn * 64 + l15) * DDIM + quad * 8;
    short8 bf[4], bfN[4];
#pragma unroll
    for (int j = 0; j < 4; ++j) bf[j] = *(const short8*)(wb + j * 16 * DDIM);

#pragma unroll
    for (int kk = 0; kk < 16; ++kk) {
      if (kk < 15) {   // prefetch next k-step's weight frags (L2-hot)
#pragma unroll
        for (int j = 0; j < 4; ++j)
          bfN[j] = *(const short8*)(wb + j * 16 * DDIM + (kk + 1) * 32);
      }
      short8 af[4];
      const int slot = ((kk * 4 + quad) ^ (l15 & 7)) * 8;
#pragma unroll
      for (int i = 0; i < 4; ++i)
        af[i] = *(const short8*)&S[(i * 16 + l15) * DDIM + slot];
#pragma unroll
      for (int i = 0; i < 4; ++i)
#pragma unroll
        for (int j = 0; j < 4; ++j)
          acc[i][j] = __builtin_amdgcn_mfma_f32_16x16x32_bf16(af[i], bf[j], acc[i][j], 0, 0, 0);
      if (kk < 15) {
#pragma unroll
        for (int j = 0; j < 4; ++j) bf[j] = bfN[j];
      }
    }

    __syncthreads();   // all waves done READING S for this layer

    float bv[4];
#pragma unroll
    for (int j = 0; j < 4; ++j) bv[j] = bias[wn * 64 + j * 16 + l15];

    if (layer < 2) {
      // write relu(acc+bias) back into S as bf16 (swizzled), in place.
      // C layout: col = lane&15 (within 16-frag), row = quad*4 + reg (m89).
#pragma unroll
      for (int i = 0; i < 4; ++i)
#pragma unroll
        for (int j = 0; j < 4; ++j) {
          int col = wn * 64 + j * 16 + l15;
#pragma unroll
          for (int r = 0; r < 4; ++r) {
            int row = i * 16 + quad * 4 + r;
            float v = fmaxf(acc[i][j][r] + bv[j], 0.f);
            S[row * DDIM + (((col >> 3) ^ (row & 7)) << 3) + (col & 7)] = f2b(v);
          }
        }
      __syncthreads();
    } else {
      // final layer: fp32 staging in two 32-row halves + residual + store.
#pragma unroll
      for (int h = 0; h < 2; ++h) {
#pragma unroll
        for (int i2 = 0; i2 < 2; ++i2) {
          int i = h * 2 + i2;
#pragma unroll
          for (int j = 0; j < 4; ++j) {
            int col = wn * 64 + j * 16 + l15;
#pragma unroll
            for (int r = 0; r < 4; ++r) {
              int row = i * 16 + quad * 4 + r;   // in [32h, 32h+32)
              int rl  = row - h * 32;
              float v = fmaxf(acc[i][j][r] + bv[j], 0.f);
              S32[rl * DDIM + (((col >> 2) ^ (rl & 7)) << 2) + (col & 3)] = v;
            }
          }
        }
        __syncthreads();
        // coalesced drain: one row of 8-col chunks per wave-iteration
#pragma unroll
        for (int it = 0; it < 4; ++it) {
          int idx = it * 512 + tid;     // 0..2047
          int r = idx >> 6, c = idx & 63;
          float4 va = *(const float4*)&S32[r * DDIM + ((((2 * c)     ^ (r & 7))) << 2)];
          float4 vb = *(const float4*)&S32[r * DDIM + ((((2 * c + 1) ^ (r & 7))) << 2)];
          long g = (rowBase + h * 32 + r) * DDIM + c * 8;
          short8 xv = *(const short8*)&A[g];
          float vv[8] = {va.x, va.y, va.z, va.w, vb.x, vb.y, vb.z, vb.w};
          short8 o;
#pragma unroll
          for (int k = 0; k < 8; ++k) o[k] = (short)f2b(vv[k] + b2f((u16)xv[k]));
          *(short8*)&A[g] = o;
        }
        __syncthreads();
      }
    }
  }
}

// --- pooling: pooled[bn][d] = mean_p feat[bn*1369+p][d] ---------------------
__global__ void zero_k(float* p, int n) {
  int i = blockIdx.x * 256 + threadIdx.x;
  if (i < n) p[i] = 0.f;
}

__global__ void pool_k(const u16* __restrict__ feat, float* __restrict__ pooled) {
  int bn = blockIdx.x, ch = blockIdx.y, d = threadIdx.x;  // block 512
  int p0 = ch * 172, p1 = p0 + 172;
  if (p1 > 1369) p1 = 1369;
  float s = 0.f;
  long base = ((long)bn * 1369 + p0) * DDIM + d;
  for (int p = p0; p < p1; ++p) { s += b2f(feat[base]); base += DDIM; }
  atomicAdd(&pooled[bn * DDIM + d], s * (1.0f / 1369.0f));
}

__global__ void gctx_k(const float* __restrict__ pooled, float* __restrict__ gctx) {
  int i = blockIdx.x * 256 + threadIdx.x;  // 32*512
  if (i >= 32 * DDIM) return;
  int b = i >> 9, d = i & 511;
  const float* p = pooled + (long)b * 3 * DDIM + d;
  gctx[i] = (p[0] + p[DDIM] + p[2 * DDIM]) * (1.0f / 3.0f);
}

// --- small fp32 linear: out[r][n] = act(in[r,:] @ W[:,n] + b[n]) ------------
template <bool RELU>
__global__ void lin_k(const float* __restrict__ in, const float* __restrict__ W,
                      const float* __restrict__ bias, float* __restrict__ out,
                      int K, int N) {
  int n = blockIdx.x * 256 + threadIdx.x;
  int r = blockIdx.y;
  if (n >= N) return;
  float acc = bias[n];
  const float* xi = in + (long)r * K;
#pragma unroll 8
  for (int k = 0; k < K; ++k) acc = fmaf(xi[k], W[(long)k * N + n], acc);
  if (RELU) acc = fmaxf(acc, 0.f);
  out[(long)r * N + n] = acc;
}

// --- pose head: 12 dots + fp64 Jacobi SVD orthogonalize + 4x4 assemble ------
__global__ void pose_k(const float* __restrict__ h,
                       const float* __restrict__ Wt, const float* __restrict__ bt,
                       const float* __restrict__ Wr, const float* __restrict__ br,
                       float* __restrict__ out) {
  int row = blockIdx.x;
  int lane = threadIdx.x;  // 64
  const float* hr = h + (long)row * DDIM;
  float part[12];
#pragma unroll
  for (int c = 0; c < 12; ++c) {
    float acc = 0.f;
    for (int k = lane; k < DDIM; k += 64) {
      float wvv = (c < 3) ? Wt[k * 3 + c] : Wr[k * 9 + (c - 3)];
      acc += hr[k] * wvv;
    }
#pragma unroll
    for (int off = 32; off > 0; off >>= 1) acc += __shfl_down(acc, off);
    part[c] = acc;
  }
  if (lane != 0) return;

  double t3[3];
  for (int i = 0; i < 3; ++i) t3[i] = (double)part[i] + (double)bt[i];
  double m[3][3];
  for (int i = 0; i < 3; ++i)
    for (int j = 0; j < 3; ++j) m[i][j] = (double)part[3 + i * 3 + j] + (double)br[i * 3 + j];
  for (int i = 0; i < 3; ++i) {
    double nn = sqrt(m[i][0] * m[i][0] + m[i][1] * m[i][1] + m[i][2] * m[i][2]);
    if (nn < 1e-12) nn = 1e-12;
    m[i][0] /= nn; m[i][1] /= nn; m[i][2] /= nn;
  }
  double Km[3][3];
  for (int a = 0; a < 3; ++a)
    for (int b = 0; b < 3; ++b) {
      double s = 0;
      for (int i = 0; i < 3; ++i) s += m[i][a] * m[i][b];
      Km[a][b] = s;
    }
  double V[3][3] = {{1, 0, 0}, {0, 1, 0}, {0, 0, 1}};
  const int PQ[3][2] = {{0, 1}, {0, 2}, {1, 2}};
  for (int sweep = 0; sweep < 20; ++sweep) {
    for (int e = 0; e < 3; ++e) {
      int p = PQ[e][0], q = PQ[e][1];
      double apq = Km[p][q];
      if (apq == 0.0) continue;
      double tau = (Km[q][q] - Km[p][p]) / (2.0 * apq);
      double tt = (tau >= 0.0 ? 1.0 : -1.0) / (fabs(tau) + sqrt(1.0 + tau * tau));
      double cc = 1.0 / sqrt(1.0 + tt * tt), ss = tt * cc;
      for (int k = 0; k < 3; ++k) { double a1 = Km[p][k], a2 = Km[q][k]; Km[p][k] = cc * a1 - ss * a2; Km[q][k] = ss * a1 + cc * a2; }
      for (int k = 0; k < 3; ++k) { double a1 = Km[k][p], a2 = Km[k][q]; Km[k][p] = cc * a1 - ss * a2; Km[k][q] = ss * a1 + cc * a2; }
      for (int k = 0; k < 3; ++k) { double a1 = V[k][p], a2 = V[k][q]; V[k][p] = cc * a1 - ss * a2; V[k][q] = ss * a1 + cc * a2; }
    }
  }
  double lam[3] = {Km[0][0], Km[1][1], Km[2][2]};
  int o0 = 0, o1 = 1, o2 = 2; double detV = 1.0;
  if (lam[o0] < lam[o1]) { int t = o0; o0 = o1; o1 = t; detV = -detV; }
  if (lam[o1] < lam[o2]) { int t = o1; o1 = o2; o2 = t; detV = -detV; }
  if (lam[o0] < lam[o1]) { int t = o0; o0 = o1; o1 = t; detV = -detV; }
  double v0[3] = {V[0][o0], V[1][o0], V[2][o0]};
  double v1[3] = {V[0][o1], V[1][o1], V[2][o1]};
  double v2[3] = {V[0][o2], V[1][o2], V[2][o2]};
  double u0[3], u1[3];
  for (int i = 0; i < 3; ++i) u0[i] = m[i][0] * v0[0] + m[i][1] * v0[1] + m[i][2] * v0[2];
  double n0 = sqrt(u0[0] * u0[0] + u0[1] * u0[1] + u0[2] * u0[2]); if (n0 < 1e-30) n0 = 1e-30;
  for (int i = 0; i < 3; ++i) u0[i] /= n0;
  for (int i = 0; i < 3; ++i) u1[i] = m[i][0] * v1[0] + m[i][1] * v1[1] + m[i][2] * v1[2];
  double d01 = u0[0] * u1[0] + u0[1] * u1[1] + u0[2] * u1[2];
  for (int i = 0; i < 3; ++i) u1[i] -= d01 * u0[i];
  double n1 = sqrt(u1[0] * u1[0] + u1[1] * u1[1] + u1[2] * u1[2]); if (n1 < 1e-30) n1 = 1e-30;
  for (int i = 0; i < 3; ++i) u1[i] /= n1;
  double u2[3] = {u0[1] * u1[2] - u0[2] * u1[1],
                  u0[2] * u1[0] - u0[0] * u1[2],
                  u0[0] * u1[1] - u0[1] * u1[0]};
  float* o = out + (long)row * 16;
  for (int i = 0; i < 3; ++i) {
    for (int j = 0; j < 3; ++j)
      o[i * 4 + j] = (float)(u0[i] * v0[j] + u1[i] * v1[j] + detV * u2[i] * v2[j]);
    o[i * 4 + 3] = (float)t3[i];
  }
  o[12] = 0.f; o[13] = 0.f; o[14] = 0.f; o[15] = 1.f;
}

// ---------------------------------------------------------------------------
extern "C" void kernel_launch(void* const* d_in, const int* in_sizes, int n_in,
                              void* d_out, int out_size, void* d_ws, size_t ws_size,
                              hipStream_t stream) {
  (void)in_sizes; (void)n_in; (void)out_size; (void)ws_size;
  const float* feat   = (const float*)d_in[0];
  const float* W_res  = (const float*)d_in[5];
  const float* b_res  = (const float*)d_in[6];
  const float* W_cur1 = (const float*)d_in[7];
  const float* b_cur1 = (const float*)d_in[8];
  const float* W_cur2 = (const float*)d_in[9];
  const float* b_cur2 = (const float*)d_in[10];
  const float* W_tp1  = (const float*)d_in[11];
  const float* b_tp1  = (const float*)d_in[12];
  const float* W_tp2  = (const float*)d_in[13];
  const float* b_tp2  = (const float*)d_in[14];
  const float* W_fut1 = (const float*)d_in[15];
  const float* b_fut1 = (const float*)d_in[16];
  const float* W_fut2 = (const float*)d_in[17];
  const float* b_fut2 = (const float*)d_in[18];
  const float* W_m1   = (const float*)d_in[19];
  const float* b_m1   = (const float*)d_in[20];
  const float* W_m2   = (const float*)d_in[21];
  const float* b_m2   = (const float*)d_in[22];
  const float* W_t    = (const float*)d_in[23];
  const float* b_t    = (const float*)d_in[24];
  const float* W_r    = (const float*)d_in[25];
  const float* b_r    = (const float*)d_in[26];

  char* ws = (char*)d_ws;
  const size_t SZ_BIG = (size_t)R_PAD * DDIM * 2;  // 134,610,944 B
  u16* A   = (u16*)(ws);                 // feat (bf16, padded) - updated in place
  u16* Wt6 = (u16*)(ws + 3 * SZ_BIG);    // 6x [512][512] bf16 transposed weights
  char* tail = ws + 3 * SZ_BIG + (size_t)6 * 512 * 512 * 2;
  float* pooled = (float*)(tail);            // [96][512]
  float* gctx   = pooled + 96 * 512;         // [32][512]
  float* tmp    = gctx + 32 * 512;           // [192][512] scratch
  float* tfb    = tmp + 192 * 512;           // [32][1536] == [96][512]
  float* allf   = tfb + 32 * 1536;           // [192][512]
  float* h2     = allf + 192 * 512;          // [192][512]
  float* outp   = (float*)d_out;

  convert_feat_k<<<65728, 256, 0, stream>>>(feat, A);
  transpose_w_k<<<6144, 256, 0, stream>>>(W_res, Wt6);

  const size_t WS1 = (size_t)512 * 512;
  // ResConvBlock 0 + 1, fully fused (3 layers + residual each)
  fused_res_k<<<2054, 512, 0, stream>>>(A, Wt6,           b_res);
  fused_res_k<<<2054, 512, 0, stream>>>(A, Wt6 + 3 * WS1, b_res + 3 * 512);

  zero_k<<<(96 * 512 + 255) / 256, 256, 0, stream>>>(pooled, 96 * 512);
  pool_k<<<dim3(96, 8), 512, 0, stream>>>(A, pooled);
  gctx_k<<<(32 * 512 + 255) / 256, 256, 0, stream>>>(pooled, gctx);

  lin_k<true ><<<dim3(2, 96),  256, 0, stream>>>(pooled, W_cur1, b_cur1, tmp, 512, 512);
  lin_k<false><<<dim3(2, 96),  256, 0, stream>>>(tmp, W_cur2, b_cur2, allf, 512, 512);
  lin_k<true ><<<dim3(2, 32),  256, 0, stream>>>(gctx, W_tp1, b_tp1, tmp, 512, 512);
  lin_k<false><<<dim3(6, 32),  256, 0, stream>>>(tmp, W_tp2, b_tp2, tfb, 512, 1536);
  lin_k<true ><<<dim3(2, 96),  256, 0, stream>>>(tfb, W_fut1, b_fut1, tmp, 512, 512);
  lin_k<false><<<dim3(2, 96),  256, 0, stream>>>(tmp, W_fut2, b_fut2, allf + 96 * 512, 512, 512);
  lin_k<true ><<<dim3(2, 192), 256, 0, stream>>>(allf, W_m1, b_m1, tmp, 512, 512);
  lin_k<true ><<<dim3(2, 192), 256, 0, stream>>>(tmp, W_m2, b_m2, h2, 512, 512);

  pose_k<<<192, 64, 0, stream>>>(h2, W_t, b_t, W_r, b_r, outp);
}